// Round 8
// baseline (364.509 us; speedup 1.0000x reference)
//
#include <hip/hip_runtime.h>
#include <hip/hip_bf16.h>

// AgentEncoder: B=256, A=512, T=21, DIM=128, SC=6, NHEAD=4, HD=32
// Round 8: cut the saturated-pipe stream. Evidence (r1/r6/r7): throughput
// invariant to occupancy 7..20 waves/CU, scales inversely with per-block
// LDS/instr stream => per-CU pipe saturated; LDS reads dominate (256
// ds_read_b128/block with 2-4x cross-wave B-frag duplication).
// Changes vs round-1 skeleton (8192 x 16-agent blocks, proven strides):
//  - conv1: each wave holds both Mt A-frags, owns p=w,w+4,w+8  (B 40->20)
//  - conv2: wave = Mt-pair x p-half split, a[2][3] in regs      (B 60->30)
//  - conv3: p outer, b[6] shared across m2 pair; A reloaded     (B 144->72)
//  - barriers 5->4 (t0-OR valid, h1-zero folded into feature phase)
//  - lgkm-only barriers (validated r7); no prefetch (r7: neutral, +VGPR)
// prep/stage2 unchanged (q-folded scores, own slim dispatches).

#define BB 256
#define AAG 512
#define TT 21
#define NAG (BB * AAG)

typedef __hip_bfloat16 bf16;
typedef __attribute__((ext_vector_type(8))) short s8v;   // 8 bf16 = 4 VGPR
typedef __attribute__((ext_vector_type(4))) float f4v;   // mfma acc

__device__ int g_dtype;        // 1 = bf16 inputs, 0 = f32 inputs
__device__ int g_mask_mode;    // 0=i32, 1=u8, 2=f32, 3=bf16
__device__ __align__(16) short g_w1p[32 * 64];    // [oc][k=tap*16+ic], pad0
__device__ __align__(16) short g_w2p[64 * 96];    // [oc][k=tap*32+ic]
__device__ __align__(16) short g_w3p[128 * 192];  // [oc][k=tap*64+ic]
__device__ __align__(16) float g_b1[32];
__device__ __align__(16) float g_b2[64];
__device__ __align__(16) float g_b3[128];
__device__ __align__(16) float g_wqk[4 * 128];    // per-head q-folded Wk
__device__ __align__(16) float g_qb[4];           // per-head q.bk

template <int DT>
__device__ __forceinline__ float ldf(const void* p, long i) {
    if (DT) return __bfloat162float(((const bf16*)p)[i]);
    return ((const float*)p)[i];
}
template <int DT>
__device__ __forceinline__ void stf(void* p, long i, float v) {
    if (DT) ((bf16*)p)[i] = __float2bfloat16(v);
    else    ((float*)p)[i] = v;
}
__device__ __forceinline__ unsigned short f2bu(float x) {
    bf16 b = __float2bfloat16(x);
    union { bf16 b; unsigned short u; } cv; cv.b = b; return cv.u;
}
__device__ __forceinline__ float bu2f(unsigned short u) {
    union { unsigned int i; float f; } cv; cv.i = ((unsigned int)u) << 16; return cv.f;
}
template <int DT>
__device__ __forceinline__ float2 ldf2(const void* p, long i) {  // i even
    if (DT) {
        unsigned int u = *(const unsigned int*)((const bf16*)p + i);
        return make_float2(bu2f((unsigned short)(u & 0xffffu)),
                           bu2f((unsigned short)(u >> 16)));
    }
    return *(const float2*)((const float*)p + i);
}
__device__ __forceinline__ bool mask_at(const void* p, long i, int mode) {
    if (mode == 0) return ((const int*)p)[i] != 0;
    if (mode == 1) return ((const unsigned char*)p)[i] != 0;
    if (mode == 2) return ((const float*)p)[i] != 0.f;
    return (((const unsigned short*)p)[i] & 0x7fff) != 0;
}

// lgkm-only barrier: orders LDS, leaves global loads/stores in flight (r7 ok).
__device__ __forceinline__ void bar_lds() {
    asm volatile("s_waitcnt lgkmcnt(0)" ::: "memory");
    __builtin_amdgcn_s_barrier();
}

// 64-element row-dot: sum_i W[off+i] * y[i], vectorized 16B loads
template <int DT>
__device__ __forceinline__ float rowdot64(const void* W, long off, const float* y) {
    float acc = 0.f;
    if (DT) {
        const unsigned short* wr = (const unsigned short*)W + off;
#pragma unroll
        for (int i = 0; i < 8; i++) {
            uint4 w = *(const uint4*)(wr + i * 8);
            acc = fmaf(bu2f((unsigned short)(w.x & 0xffffu)), y[i * 8 + 0], acc);
            acc = fmaf(bu2f((unsigned short)(w.x >> 16)),     y[i * 8 + 1], acc);
            acc = fmaf(bu2f((unsigned short)(w.y & 0xffffu)), y[i * 8 + 2], acc);
            acc = fmaf(bu2f((unsigned short)(w.y >> 16)),     y[i * 8 + 3], acc);
            acc = fmaf(bu2f((unsigned short)(w.z & 0xffffu)), y[i * 8 + 4], acc);
            acc = fmaf(bu2f((unsigned short)(w.z >> 16)),     y[i * 8 + 5], acc);
            acc = fmaf(bu2f((unsigned short)(w.w & 0xffffu)), y[i * 8 + 6], acc);
            acc = fmaf(bu2f((unsigned short)(w.w >> 16)),     y[i * 8 + 7], acc);
        }
    } else {
        const float* wr = (const float*)W + off;
#pragma unroll
        for (int i = 0; i < 16; i++) {
            float4 w = *(const float4*)(wr + i * 4);
            acc = fmaf(w.x, y[i * 4 + 0], acc);
            acc = fmaf(w.y, y[i * 4 + 1], acc);
            acc = fmaf(w.z, y[i * 4 + 2], acc);
            acc = fmaf(w.w, y[i * 4 + 3], acc);
        }
    }
    return acc;
}

// ---------------- weight pad/transpose/cast (grid-stride over 64 blocks) ----------------
template <int DT>
__device__ __forceinline__ void prep_body(const void* w1, const void* b1,
                                          const void* w2, const void* b2,
                                          const void* w3, const void* b3) {
    int tid = blockIdx.x * 256 + threadIdx.x;
    const int nt = 64 * 256;
    for (int i = tid; i < 32 * 64; i += nt) {
        int oc = i >> 6, k = i & 63, tap = k >> 4, ic = k & 15;
        float v = (tap < 3 && ic < 9) ? ldf<DT>(w1, oc * 27 + ic * 3 + tap) : 0.f;
        g_w1p[i] = (short)f2bu(v);
    }
    for (int i = tid; i < 64 * 96; i += nt) {
        int oc = i / 96, k = i % 96, tap = k >> 5, ic = k & 31;
        g_w2p[i] = (short)f2bu(ldf<DT>(w2, oc * 96 + ic * 3 + tap));
    }
    for (int i = tid; i < 128 * 192; i += nt) {
        int oc = i / 192, k = i % 192, tap = k >> 6, ic = k & 63;
        g_w3p[i] = (short)f2bu(ldf<DT>(w3, oc * 192 + ic * 3 + tap));
    }
    for (int i = tid; i < 32; i += nt) g_b1[i] = ldf<DT>(b1, i);
    for (int i = tid; i < 64; i += nt) g_b2[i] = ldf<DT>(b2, i);
    for (int i = tid; i < 128; i += nt) g_b3[i] = ldf<DT>(b3, i);
}

// block 64: q = query@Wq^T+bq, then fold through Wk: g_wqk[h][e], g_qb[h]
template <int DT>
__device__ __forceinline__ void qprep_body(const void* query, const void* ipw,
                                           const void* ipb, float* sq) {
    int tid = threadIdx.x;
    if (tid < 128) {
        float acc = ldf<DT>(ipb, tid);
        for (int e = 0; e < 128; e++)
            acc = fmaf(ldf<DT>(query, e), ldf<DT>(ipw, (long)tid * 128 + e), acc);
        sq[tid] = acc;
    }
    __syncthreads();
    int e = tid & 127, hb = tid >> 7;
    for (int h = hb; h < 4; h += 2) {
        float acc = 0.f;
#pragma unroll
        for (int j = 0; j < 32; j++)
            acc = fmaf(sq[h * 32 + j], ldf<DT>(ipw, (long)(128 + h * 32 + j) * 128 + e), acc);
        g_wqk[h * 128 + e] = acc;
    }
    if (tid < 4) {
        float acc = 0.f;
#pragma unroll
        for (int j = 0; j < 32; j++)
            acc = fmaf(sq[tid * 32 + j], ldf<DT>(ipb, 128 + tid * 32 + j), acc);
        g_qb[tid] = acc;
    }
}

// ---------------- launch A: per-block detect + prep + q-fold ----------------
__global__ __launch_bounds__(256) void prep_kernel(
    const unsigned int* __restrict__ pw, const unsigned char* __restrict__ m,
    const void* __restrict__ w1, const void* __restrict__ b1,
    const void* __restrict__ w2, const void* __restrict__ b2,
    const void* __restrict__ w3, const void* __restrict__ b3,
    const void* __restrict__ query, const void* __restrict__ ipw,
    const void* __restrict__ ipb) {
    __shared__ int cls[4];
    __shared__ int mv;
    __shared__ int good;
    __shared__ float sq[128];
    int tid = threadIdx.x;
    if (tid < 4) cls[tid] = 0;
    if (tid == 0) { mv = 0; good = 0; }
    __syncthreads();
    int g = 0;
    for (int i = tid; i < 1024; i += 256) {
        unsigned int w = pw[i];
        unsigned int h0 = w & 0xffffu, h1 = w >> 16;
        unsigned int e0 = (h0 >> 7) & 0xff, e1 = (h1 >> 7) & 0xff;
        if (h0 == 0 || (e0 >= 90 && e0 <= 160)) g++;
        if (h1 == 0 || (e1 >= 90 && e1 <= 160)) g++;
    }
    atomicAdd(&good, g);
    int l0 = 0, l1 = 0, l2 = 0, l3 = 0, lm = 0;
    for (int i = tid; i < 4096; i += 256) {
        int v = m[i];
        if (v) {
            switch (i & 3) { case 0: l0 = 1; break; case 1: l1 = 1; break;
                             case 2: l2 = 1; break; default: l3 = 1; }
            if (v > lm) lm = v;
        }
    }
    if (l0) atomicOr(&cls[0], 1);
    if (l1) atomicOr(&cls[1], 1);
    if (l2) atomicOr(&cls[2], 1);
    if (l3) atomicOr(&cls[3], 1);
    atomicMax(&mv, lm);
    __syncthreads();
    int dt = (good >= 1740) ? 1 : 0;
    int mode;
    if (!cls[1] && !cls[2] && !cls[3]) mode = 0;
    else if (!cls[0] && !cls[1])       mode = 2;
    else if (mv <= 1)                  mode = 1;
    else                               mode = 3;
    if (blockIdx.x == 0 && tid == 0) { g_dtype = dt; g_mask_mode = mode; }

    if (blockIdx.x < 64) {
        if (dt) prep_body<1>(w1, b1, w2, b2, w3, b3);
        else    prep_body<0>(w1, b1, w2, b2, w3, b3);
    } else {
        if (dt) qprep_body<1>(query, ipw, ipb, sq);
        else    qprep_body<0>(query, ipw, ipb, sq);
    }
}

// ---------------- stage 1: 16 agents/block, 4 waves, 4 barriers ----------------
// LDS (shorts). Region A: feat [16][FEAT_AS], reused as h2. Region B: h1
// [16][H1_AS], reused as c3. Measured round-1 strides (2-way bank alias).
#define FEAT_RS 24     // rows t=0..21 (20/21 zero); 48 B
#define FEAT_AS 568    // 1136 B == -4 banks (mod 32)
#define H1_RS 40       // rows t=0..10 (10 zero); 80 B
#define H1_AS 440      // 880 B == -4 banks
#define H2_RS 72       // rows r=0..6 (0,6 zero); 144 B
#define H2_AS 504      // 1008 B == -4 banks
#define C3_AS 392      // 3*128 + 8 pad; 784 B == +4 banks
#define OFF_H1 9088    // shorts = 16*FEAT_AS
#define OFF_VALID 32256 // bytes
#define SMEM_BYTES 32320 // -> 32768 alloc => 5 blocks/CU (LDS cap)

#define MFMA16(a, b, c) __builtin_amdgcn_mfma_f32_16x16x32_bf16((a), (b), (c), 0, 0, 0)

__device__ __forceinline__ uint2 pack_relu(f4v acc, f4v bia) {
    unsigned int lo = f2bu(fmaxf(acc[0] + bia[0], 0.f)) | ((unsigned int)f2bu(fmaxf(acc[1] + bia[1], 0.f)) << 16);
    unsigned int hi = f2bu(fmaxf(acc[2] + bia[2], 0.f)) | ((unsigned int)f2bu(fmaxf(acc[3] + bia[3], 0.f)) << 16);
    return make_uint2(lo, hi);
}

template <int DT>
__device__ __forceinline__ void stage1_body(
    const void* pos, const void* heading, const void* vel, const void* shp,
    const void* vmask, const int* category, const void* type_emb, void* out,
    char* smem, long agent0) {
    short* feat = (short*)smem;               // region A
    short* h1   = (short*)smem + OFF_H1;      // region B
    short* h2   = (short*)smem;               // region A reuse (feat dead after conv1)
    short* c3   = (short*)smem + OFF_H1;      // region B reuse (h1 dead after conv2)
    int* s_valid = (int*)(smem + OFF_VALID);

    const int tid = threadIdx.x;
    const int wave = tid >> 6, lane = tid & 63;
    const int col = lane & 15, quad = lane >> 4;
    const int mode = g_mask_mode;

    // ---- phase 1: feature build + h1 zero row + per-agent valid (t0-OR) ----
    {
        unsigned int* h1u = (unsigned int*)h1;          // h1 row 10 zero
        h1u[(tid >> 4) * 220 + 200 + (tid & 15)] = 0;
    }
    for (int idx = tid; idx < 16 * 22; idx += 256) {
        int ag = idx / 22, t = idx % 22;
        short* row = feat + ag * FEAT_AS + t * FEAT_RS;
        long agl = agent0 + ag;
        if (t == 0) {                       // direct OR over the agent's 21 masks
            long b0 = agl * TT;
            int v = 0;
#pragma unroll
            for (int tt = 0; tt < TT; tt++)
                v |= mask_at(vmask, b0 + tt, mode) ? 1 : 0;
            s_valid[ag] = v;
        }
        if (t >= 20) {
            *(uint4*)row = make_uint4(0, 0, 0, 0);
            *(uint4*)(row + 8) = make_uint4(0, 0, 0, 0);
        } else {
            long base = agl * TT + t;
            bool vmt = mask_at(vmask, base, mode);
            bool m2 = vmt && mask_at(vmask, base + 1, mode);
            float2 pa = ldf2<DT>(pos, base * 2), pb = ldf2<DT>(pos, base * 2 + 2);
            float2 va = ldf2<DT>(vel, base * 2), vb = ldf2<DT>(vel, base * 2 + 2);
            float hh0 = ldf<DT>(heading, base), hh1 = ldf<DT>(heading, base + 1);
            float2 sv = ldf2<DT>(shp, base * 2 + 2);
            float dh = m2 ? (hh1 - hh0) : 0.f;      // masked: cos=1, sin=0 (ref)
            float sn, cn;
            __sincosf(dh, &sn, &cn);
            unsigned int p0 = f2bu(m2 ? pb.x - pa.x : 0.f) | ((unsigned int)f2bu(m2 ? pb.y - pa.y : 0.f) << 16);
            unsigned int p1 = f2bu(m2 ? vb.x - va.x : 0.f) | ((unsigned int)f2bu(m2 ? vb.y - va.y : 0.f) << 16);
            unsigned int p2 = f2bu(cn) | ((unsigned int)f2bu(sn) << 16);
            unsigned int p3 = f2bu(sv.x) | ((unsigned int)f2bu(sv.y) << 16);
            unsigned int p4 = (unsigned int)f2bu(m2 ? 1.f : 0.f);
            *(uint4*)row = make_uint4(p0, p1, p2, p3);
            *(uint4*)(row + 8) = make_uint4(p4, 0, 0, 0);
        }
    }
    bar_lds();

    // ---- conv1: both Mt per wave (A in regs), p = wave,wave+4,wave+8 ----
    // B-reads: 2 per p, 20/block (was 40).
    {
        s8v a00 = *(const s8v*)(g_w1p + col * 64 + quad * 8);
        s8v a01 = *(const s8v*)(g_w1p + col * 64 + 32 + quad * 8);
        s8v a10 = *(const s8v*)(g_w1p + (16 + col) * 64 + quad * 8);
        s8v a11 = *(const s8v*)(g_w1p + (16 + col) * 64 + 32 + quad * 8);
        f4v bia0 = *(const f4v*)(g_b1 + quad * 4);
        f4v bia1 = *(const f4v*)(g_b1 + 16 + quad * 4);
        int k0 = quad * 8, k1 = 32 + quad * 8;
        int tap0 = k0 >> 4, ic0 = k0 & 15;
        int tap1 = k1 >> 4, ic1 = k1 & 15;
        const short* agbase = feat + col * FEAT_AS;
        for (int p = wave; p < 10; p += 4) {
            const short* bb = agbase + 2 * p * FEAT_RS;
            s8v b0 = *(const s8v*)(bb + tap0 * FEAT_RS + ic0);
            s8v b1 = *(const s8v*)(bb + tap1 * FEAT_RS + ic1);
            f4v acc0 = {0.f, 0.f, 0.f, 0.f}, acc1 = {0.f, 0.f, 0.f, 0.f};
            acc0 = MFMA16(a00, b0, acc0); acc0 = MFMA16(a01, b1, acc0);
            acc1 = MFMA16(a10, b0, acc1); acc1 = MFMA16(a11, b1, acc1);
            short* wr = h1 + col * H1_AS + p * H1_RS + quad * 4;
            *(uint2*)wr = pack_relu(acc0, bia0);
            *(uint2*)(wr + 16) = pack_relu(acc1, bia1);
        }
    }
    bar_lds();

    // ---- conv2: wave = Mt-pair (wave>>1) x p-half (wave&1); b[3] shared
    //      across the 2 Mt. B-reads: 30/block (was 60). Zero h2 rows 0,6 first ----
    {
        unsigned int* h2u = (unsigned int*)h2;
        for (int i = tid; i < 1024; i += 256) {
            int a2 = i >> 6, r = (i >> 5) & 1, cc = i & 31;
            h2u[a2 * 252 + r * 216 + cc] = 0;
        }
        int mt2 = wave >> 1;                   // Mt pair {2*mt2, 2*mt2+1}
        int nh = wave & 1;                     // p subset: 0 -> 0..2, 1 -> 3..4
        s8v a0[3], a1[3];
#pragma unroll
        for (int ks = 0; ks < 3; ks++) {
            a0[ks] = *(const s8v*)(g_w2p + ((mt2 * 2) * 16 + col) * 96 + ks * 32 + quad * 8);
            a1[ks] = *(const s8v*)(g_w2p + ((mt2 * 2 + 1) * 16 + col) * 96 + ks * 32 + quad * 8);
        }
        f4v bia0 = *(const f4v*)(g_b2 + (mt2 * 2) * 16 + quad * 4);
        f4v bia1 = *(const f4v*)(g_b2 + (mt2 * 2 + 1) * 16 + quad * 4);
        int pbeg = nh * 3, pend = nh ? 5 : 3;
        for (int p = pbeg; p < pend; p++) {
            const short* bb = h1 + col * H1_AS + 2 * p * H1_RS + quad * 8;
            s8v b0 = *(const s8v*)(bb);
            s8v b1 = *(const s8v*)(bb + H1_RS);
            s8v b2 = *(const s8v*)(bb + 2 * H1_RS);
            f4v acc0 = {0.f, 0.f, 0.f, 0.f}, acc1 = {0.f, 0.f, 0.f, 0.f};
            acc0 = MFMA16(a0[0], b0, acc0); acc0 = MFMA16(a0[1], b1, acc0); acc0 = MFMA16(a0[2], b2, acc0);
            acc1 = MFMA16(a1[0], b0, acc1); acc1 = MFMA16(a1[1], b1, acc1); acc1 = MFMA16(a1[2], b2, acc1);
            short* wr = h2 + col * H2_AS + (p + 1) * H2_RS + (mt2 * 2) * 16 + quad * 4;
            *(uint2*)wr = pack_relu(acc0, bia0);
            *(uint2*)(wr + 16) = pack_relu(acc1, bia1);
        }
    }
    bar_lds();

    // ---- conv3: p outer, b[6] shared across the wave's Mt pair; A reloaded
    //      per (p, Mt) from L2-resident g_w3p. B-reads: 72/block (was 144) ----
#pragma unroll
    for (int p = 0; p < 3; p++) {
        s8v b[6];
#pragma unroll
        for (int ks = 0; ks < 6; ks++) {
            int kg = ks * 32 + quad * 8;
            int tap = kg >> 6, ic = kg & 63;
            b[ks] = *(const s8v*)(h2 + col * H2_AS + (2 * p + tap) * H2_RS + ic);
        }
#pragma unroll
        for (int m2 = 0; m2 < 2; m2++) {
            int Mt = wave * 2 + m2;
            int oc = Mt * 16 + col;
            f4v acc = {0.f, 0.f, 0.f, 0.f};
#pragma unroll
            for (int ks = 0; ks < 6; ks++) {
                s8v a = *(const s8v*)(g_w3p + oc * 192 + ks * 32 + quad * 8);
                acc = MFMA16(a, b[ks], acc);
            }
            f4v bia = *(const f4v*)(g_b3 + Mt * 16 + quad * 4);
            *(uint2*)(c3 + col * C3_AS + p * 128 + Mt * 16 + quad * 4) =
                pack_relu(acc, bia);
        }
    }
    bar_lds();

    // ---- epilogue: mean over 3 p, valid mask, + type_emb (coalesced rows) ----
    {
        int ag = tid >> 4;
        int ocg = (tid & 15) * 8;
        const short* cb = c3 + ag * C3_AS;
        s8v x0 = *(const s8v*)(cb + ocg);
        s8v x1 = *(const s8v*)(cb + 128 + ocg);
        s8v x2 = *(const s8v*)(cb + 256 + ocg);
        int valid = s_valid[ag];
        long agl = agent0 + ag;
        int cat = category[agl];
        float vals[8];
#pragma unroll
        for (int j = 0; j < 8; j++) {
            float m = (bu2f((unsigned short)x0[j]) + bu2f((unsigned short)x1[j]) +
                       bu2f((unsigned short)x2[j])) * (1.f / 3.f);
            vals[j] = valid ? m : 0.f;
        }
        if (DT) {
            s8v te = *(const s8v*)((const bf16*)type_emb + (long)cat * 128 + ocg);
            s8v o;
#pragma unroll
            for (int j = 0; j < 8; j++)
                o[j] = (short)f2bu(vals[j] + bu2f((unsigned short)te[j]));
            *(s8v*)((bf16*)out + agl * 128 + ocg) = o;
        } else {
            const float4* tep = (const float4*)((const float*)type_emb + (long)cat * 128 + ocg);
            float4 t0 = tep[0], t1 = tep[1];
            float4 o0 = make_float4(vals[0] + t0.x, vals[1] + t0.y, vals[2] + t0.z, vals[3] + t0.w);
            float4 o1 = make_float4(vals[4] + t1.x, vals[5] + t1.y, vals[6] + t1.z, vals[7] + t1.w);
            float4* op = (float4*)((float*)out + agl * 128 + ocg);
            op[0] = o0; op[1] = o1;
        }
    }
}

__global__ __launch_bounds__(256) void stage1_kernel(
    const void* __restrict__ pos, const void* __restrict__ heading,
    const void* __restrict__ vel, const void* __restrict__ shp,
    const void* __restrict__ vmask, const int* __restrict__ category,
    const void* __restrict__ type_emb, void* __restrict__ out) {
    __shared__ __align__(16) char smem[SMEM_BYTES];
    long agent0 = (long)blockIdx.x * 16;
    if (g_dtype) stage1_body<1>(pos, heading, vel, shp, vmask, category, type_emb, out, smem, agent0);
    else         stage1_body<0>(pos, heading, vel, shp, vmask, category, type_emb, out, smem, agent0);
}

// ---------------- stage 2 (256 threads): ego cross-attention, overwrites out[b][0] ----------------
template <int DT>
__device__ __forceinline__ void stage2_body(
    const void* cs, const int* category,
    const void* se_w, const void* se_b, const void* pe,
    const void* ipw, const void* ipb, const void* opw, const void* opb,
    const void* type_emb, void* out, float* sm) {
    const int b = blockIdx.x;
    const int tid = threadIdx.x;
    const int d = tid & 127, half = tid >> 7;

    float* s_xe  = sm;                  // [6][128]
    float* s_y   = s_xe + 768;          // [4][128]
    float* s_sc  = s_y + 512;           // [24] (+pad)
    float* s_att = s_sc + 32;           // [24] (+pad)
    float* s_o   = s_att + 32;          // [128]
    float* s_par = s_o + 128;           // [2][128]

    for (int idx = tid; idx < 768; idx += 256) {
        int s = idx >> 7, dd = idx & 127;
        float ego = ldf<DT>(cs, b * 6 + s);
        s_xe[idx] = fmaf(ego, ldf<DT>(se_w, s * 128 + dd),
                         ldf<DT>(se_b, s * 128 + dd) + ldf<DT>(pe, s * 128 + dd));
    }
    __syncthreads();

    if (tid < 96) {
        int g = tid >> 2, lig = tid & 3;
        int h = g / 6, s = g - h * 6;
        const float* xr = s_xe + s * 128 + lig * 32;
        const float* wr = g_wqk + h * 128 + lig * 32;
        float t = 0.f;
#pragma unroll
        for (int e = 0; e < 32; e++) t = fmaf(xr[e], wr[e], t);
        t += __shfl_xor(t, 1, 4);
        t += __shfl_xor(t, 2, 4);
        if (lig == 0) s_sc[g] = (t + g_qb[h]) * 0.17677669529663687f;
    }
    __syncthreads();

    if (tid < 4) {
        float mx = -1e30f;
#pragma unroll
        for (int s = 0; s < 6; s++) mx = fmaxf(mx, s_sc[tid * 6 + s]);
        float sum = 0.f, ex[6];
#pragma unroll
        for (int s = 0; s < 6; s++) { ex[s] = expf(s_sc[tid * 6 + s] - mx); sum += ex[s]; }
        float inv = 1.f / sum;
#pragma unroll
        for (int s = 0; s < 6; s++) s_att[tid * 6 + s] = ex[s] * inv;
    }
    __syncthreads();

    for (int idx = tid; idx < 512; idx += 256) {
        int h = idx >> 7, e = idx & 127;
        float y = 0.f;
#pragma unroll
        for (int s = 0; s < 6; s++) y = fmaf(s_att[h * 6 + s], s_xe[s * 128 + e], y);
        s_y[idx] = y;
    }
    __syncthreads();

    {
        int h = d >> 5;
        const float* yr = s_y + h * 128 + half * 64;
        s_par[half * 128 + d] = rowdot64<DT>(ipw, (long)(256 + d) * 128 + half * 64, yr);
    }
    __syncthreads();
    if (half == 0) s_o[d] = s_par[d] + s_par[128 + d] + ldf<DT>(ipb, 256 + d);
    __syncthreads();

    {
        const float* orr = s_o + half * 64;
        s_par[half * 128 + d] = rowdot64<DT>(opw, (long)d * 128 + half * 64, orr);
    }
    __syncthreads();
    if (half == 0) {
        float x = s_par[d] + s_par[128 + d] + ldf<DT>(opb, d);
        int cat = category[(long)b * AAG];
        stf<DT>(out, (long)b * AAG * 128 + d, x + ldf<DT>(type_emb, cat * 128 + d));
    }
}

__global__ __launch_bounds__(256) void stage2_kernel(
    const void* __restrict__ cs, const int* __restrict__ category,
    const void* __restrict__ se_w, const void* __restrict__ se_b,
    const void* __restrict__ pe,
    const void* __restrict__ ipw, const void* __restrict__ ipb,
    const void* __restrict__ opw, const void* __restrict__ opb,
    const void* __restrict__ type_emb, void* __restrict__ out) {
    __shared__ float sm[1728];
    if (g_dtype) stage2_body<1>(cs, category, se_w, se_b, pe, ipw, ipb, opw, opb, type_emb, out, sm);
    else         stage2_body<0>(cs, category, se_w, se_b, pe, ipw, ipb, opw, opb, type_emb, out, sm);
}

extern "C" void kernel_launch(void* const* d_in, const int* in_sizes, int n_in,
                              void* d_out, int out_size, void* d_ws, size_t ws_size,
                              hipStream_t stream) {
    const void* position      = d_in[0];
    const void* heading       = d_in[1];
    const void* velocity      = d_in[2];
    const void* shape         = d_in[3];
    const void* current_state = d_in[4];
    const int*  category      = (const int*)d_in[5];
    const void* valid_mask    = d_in[6];
    const void* conv1_w = d_in[7];
    const void* conv1_b = d_in[8];
    const void* conv2_w = d_in[9];
    const void* conv2_b = d_in[10];
    const void* conv3_w = d_in[11];
    const void* conv3_b = d_in[12];
    const void* se_w    = d_in[13];
    const void* se_b    = d_in[14];
    const void* pos_embed = d_in[15];
    const void* query     = d_in[16];
    const void* in_proj_w = d_in[17];
    const void* in_proj_b = d_in[18];
    const void* out_proj_w = d_in[19];
    const void* out_proj_b = d_in[20];
    const void* type_emb   = d_in[21];

    hipLaunchKernelGGL(prep_kernel, dim3(65), dim3(256), 0, stream,
                       (const unsigned int*)position, (const unsigned char*)valid_mask,
                       conv1_w, conv1_b, conv2_w, conv2_b, conv3_w, conv3_b,
                       query, in_proj_w, in_proj_b);

    hipLaunchKernelGGL(stage1_kernel, dim3(NAG / 16), dim3(256), 0, stream,
                       position, heading, velocity, shape, valid_mask, category,
                       type_emb, d_out);

    hipLaunchKernelGGL(stage2_kernel, dim3(BB), dim3(256), 0, stream,
                       current_state, category, se_w, se_b, pos_embed,
                       in_proj_w, in_proj_b, out_proj_w, out_proj_b, type_emb, d_out);
}

// Round 9
// 357.961 us; speedup vs baseline: 1.0183x; 1.0183x over previous
//
#include <hip/hip_runtime.h>
#include <hip/hip_bf16.h>

// AgentEncoder: B=256, A=512, T=21, DIM=128, SC=6, NHEAD=4, HD=32
// Round 9: clean LDS-cut experiment. r8 post-mortem: its conv3 reloaded A from
// global inside the inner loop (12->36 loads/wave, serial L2 latency) - that,
// not the LDS cut, caused 131->204. This round:
//  - conv1/conv2: r8 forms (B-reads 100->50, no global adds) [r8-verified]
//  - conv3: BOTH Mt A-frag sets hoisted (a0[6],a1[6], 12 global loads as r1),
//    b[6] shared across the Mt pair => B-reads 144->72, A register-resident.
//  - conv3 epilogue: p-accumulators are lane-local (ag=col) => in-reg f32
//    relu-mean (r5 idea), single bf16 write/Mt; LDS-staged COALESCED epilogue
//    kept (r5's failure was scattered global stores, not the mean).
//    C3_AS=136 (272B == +4 banks, 2-way).
//  - 4 barriers, lgkm-only (r7-validated); no prefetch.
// Per block: LDS reads 256->~126, writes ~100->~65, globals unchanged vs r1.
// VGPR ~100 => ~16 waves/CU (r1/r6/r7: throughput invariant 7-20 waves/CU).

#define BB 256
#define AAG 512
#define TT 21
#define NAG (BB * AAG)

typedef __hip_bfloat16 bf16;
typedef __attribute__((ext_vector_type(8))) short s8v;   // 8 bf16 = 4 VGPR
typedef __attribute__((ext_vector_type(4))) float f4v;   // mfma acc

__device__ int g_dtype;        // 1 = bf16 inputs, 0 = f32 inputs
__device__ int g_mask_mode;    // 0=i32, 1=u8, 2=f32, 3=bf16
__device__ __align__(16) short g_w1p[32 * 64];    // [oc][k=tap*16+ic], pad0
__device__ __align__(16) short g_w2p[64 * 96];    // [oc][k=tap*32+ic]
__device__ __align__(16) short g_w3p[128 * 192];  // [oc][k=tap*64+ic]
__device__ __align__(16) float g_b1[32];
__device__ __align__(16) float g_b2[64];
__device__ __align__(16) float g_b3[128];
__device__ __align__(16) float g_wqk[4 * 128];    // per-head q-folded Wk
__device__ __align__(16) float g_qb[4];           // per-head q.bk

template <int DT>
__device__ __forceinline__ float ldf(const void* p, long i) {
    if (DT) return __bfloat162float(((const bf16*)p)[i]);
    return ((const float*)p)[i];
}
template <int DT>
__device__ __forceinline__ void stf(void* p, long i, float v) {
    if (DT) ((bf16*)p)[i] = __float2bfloat16(v);
    else    ((float*)p)[i] = v;
}
__device__ __forceinline__ unsigned short f2bu(float x) {
    bf16 b = __float2bfloat16(x);
    union { bf16 b; unsigned short u; } cv; cv.b = b; return cv.u;
}
__device__ __forceinline__ float bu2f(unsigned short u) {
    union { unsigned int i; float f; } cv; cv.i = ((unsigned int)u) << 16; return cv.f;
}
template <int DT>
__device__ __forceinline__ float2 ldf2(const void* p, long i) {  // i even
    if (DT) {
        unsigned int u = *(const unsigned int*)((const bf16*)p + i);
        return make_float2(bu2f((unsigned short)(u & 0xffffu)),
                           bu2f((unsigned short)(u >> 16)));
    }
    return *(const float2*)((const float*)p + i);
}
__device__ __forceinline__ bool mask_at(const void* p, long i, int mode) {
    if (mode == 0) return ((const int*)p)[i] != 0;
    if (mode == 1) return ((const unsigned char*)p)[i] != 0;
    if (mode == 2) return ((const float*)p)[i] != 0.f;
    return (((const unsigned short*)p)[i] & 0x7fff) != 0;
}

// lgkm-only barrier: orders LDS, leaves global loads/stores in flight (r7 ok).
__device__ __forceinline__ void bar_lds() {
    asm volatile("s_waitcnt lgkmcnt(0)" ::: "memory");
    __builtin_amdgcn_s_barrier();
}

// 64-element row-dot: sum_i W[off+i] * y[i], vectorized 16B loads
template <int DT>
__device__ __forceinline__ float rowdot64(const void* W, long off, const float* y) {
    float acc = 0.f;
    if (DT) {
        const unsigned short* wr = (const unsigned short*)W + off;
#pragma unroll
        for (int i = 0; i < 8; i++) {
            uint4 w = *(const uint4*)(wr + i * 8);
            acc = fmaf(bu2f((unsigned short)(w.x & 0xffffu)), y[i * 8 + 0], acc);
            acc = fmaf(bu2f((unsigned short)(w.x >> 16)),     y[i * 8 + 1], acc);
            acc = fmaf(bu2f((unsigned short)(w.y & 0xffffu)), y[i * 8 + 2], acc);
            acc = fmaf(bu2f((unsigned short)(w.y >> 16)),     y[i * 8 + 3], acc);
            acc = fmaf(bu2f((unsigned short)(w.z & 0xffffu)), y[i * 8 + 4], acc);
            acc = fmaf(bu2f((unsigned short)(w.z >> 16)),     y[i * 8 + 5], acc);
            acc = fmaf(bu2f((unsigned short)(w.w & 0xffffu)), y[i * 8 + 6], acc);
            acc = fmaf(bu2f((unsigned short)(w.w >> 16)),     y[i * 8 + 7], acc);
        }
    } else {
        const float* wr = (const float*)W + off;
#pragma unroll
        for (int i = 0; i < 16; i++) {
            float4 w = *(const float4*)(wr + i * 4);
            acc = fmaf(w.x, y[i * 4 + 0], acc);
            acc = fmaf(w.y, y[i * 4 + 1], acc);
            acc = fmaf(w.z, y[i * 4 + 2], acc);
            acc = fmaf(w.w, y[i * 4 + 3], acc);
        }
    }
    return acc;
}

// ---------------- weight pad/transpose/cast (grid-stride over 64 blocks) ----------------
template <int DT>
__device__ __forceinline__ void prep_body(const void* w1, const void* b1,
                                          const void* w2, const void* b2,
                                          const void* w3, const void* b3) {
    int tid = blockIdx.x * 256 + threadIdx.x;
    const int nt = 64 * 256;
    for (int i = tid; i < 32 * 64; i += nt) {
        int oc = i >> 6, k = i & 63, tap = k >> 4, ic = k & 15;
        float v = (tap < 3 && ic < 9) ? ldf<DT>(w1, oc * 27 + ic * 3 + tap) : 0.f;
        g_w1p[i] = (short)f2bu(v);
    }
    for (int i = tid; i < 64 * 96; i += nt) {
        int oc = i / 96, k = i % 96, tap = k >> 5, ic = k & 31;
        g_w2p[i] = (short)f2bu(ldf<DT>(w2, oc * 96 + ic * 3 + tap));
    }
    for (int i = tid; i < 128 * 192; i += nt) {
        int oc = i / 192, k = i % 192, tap = k >> 6, ic = k & 63;
        g_w3p[i] = (short)f2bu(ldf<DT>(w3, oc * 192 + ic * 3 + tap));
    }
    for (int i = tid; i < 32; i += nt) g_b1[i] = ldf<DT>(b1, i);
    for (int i = tid; i < 64; i += nt) g_b2[i] = ldf<DT>(b2, i);
    for (int i = tid; i < 128; i += nt) g_b3[i] = ldf<DT>(b3, i);
}

// block 64: q = query@Wq^T+bq, then fold through Wk: g_wqk[h][e], g_qb[h]
template <int DT>
__device__ __forceinline__ void qprep_body(const void* query, const void* ipw,
                                           const void* ipb, float* sq) {
    int tid = threadIdx.x;
    if (tid < 128) {
        float acc = ldf<DT>(ipb, tid);
        for (int e = 0; e < 128; e++)
            acc = fmaf(ldf<DT>(query, e), ldf<DT>(ipw, (long)tid * 128 + e), acc);
        sq[tid] = acc;
    }
    __syncthreads();
    int e = tid & 127, hb = tid >> 7;
    for (int h = hb; h < 4; h += 2) {
        float acc = 0.f;
#pragma unroll
        for (int j = 0; j < 32; j++)
            acc = fmaf(sq[h * 32 + j], ldf<DT>(ipw, (long)(128 + h * 32 + j) * 128 + e), acc);
        g_wqk[h * 128 + e] = acc;
    }
    if (tid < 4) {
        float acc = 0.f;
#pragma unroll
        for (int j = 0; j < 32; j++)
            acc = fmaf(sq[tid * 32 + j], ldf<DT>(ipb, 128 + tid * 32 + j), acc);
        g_qb[tid] = acc;
    }
}

// ---------------- launch A: per-block detect + prep + q-fold ----------------
__global__ __launch_bounds__(256) void prep_kernel(
    const unsigned int* __restrict__ pw, const unsigned char* __restrict__ m,
    const void* __restrict__ w1, const void* __restrict__ b1,
    const void* __restrict__ w2, const void* __restrict__ b2,
    const void* __restrict__ w3, const void* __restrict__ b3,
    const void* __restrict__ query, const void* __restrict__ ipw,
    const void* __restrict__ ipb) {
    __shared__ int cls[4];
    __shared__ int mv;
    __shared__ int good;
    __shared__ float sq[128];
    int tid = threadIdx.x;
    if (tid < 4) cls[tid] = 0;
    if (tid == 0) { mv = 0; good = 0; }
    __syncthreads();
    int g = 0;
    for (int i = tid; i < 1024; i += 256) {
        unsigned int w = pw[i];
        unsigned int h0 = w & 0xffffu, h1 = w >> 16;
        unsigned int e0 = (h0 >> 7) & 0xff, e1 = (h1 >> 7) & 0xff;
        if (h0 == 0 || (e0 >= 90 && e0 <= 160)) g++;
        if (h1 == 0 || (e1 >= 90 && e1 <= 160)) g++;
    }
    atomicAdd(&good, g);
    int l0 = 0, l1 = 0, l2 = 0, l3 = 0, lm = 0;
    for (int i = tid; i < 4096; i += 256) {
        int v = m[i];
        if (v) {
            switch (i & 3) { case 0: l0 = 1; break; case 1: l1 = 1; break;
                             case 2: l2 = 1; break; default: l3 = 1; }
            if (v > lm) lm = v;
        }
    }
    if (l0) atomicOr(&cls[0], 1);
    if (l1) atomicOr(&cls[1], 1);
    if (l2) atomicOr(&cls[2], 1);
    if (l3) atomicOr(&cls[3], 1);
    atomicMax(&mv, lm);
    __syncthreads();
    int dt = (good >= 1740) ? 1 : 0;
    int mode;
    if (!cls[1] && !cls[2] && !cls[3]) mode = 0;
    else if (!cls[0] && !cls[1])       mode = 2;
    else if (mv <= 1)                  mode = 1;
    else                               mode = 3;
    if (blockIdx.x == 0 && tid == 0) { g_dtype = dt; g_mask_mode = mode; }

    if (blockIdx.x < 64) {
        if (dt) prep_body<1>(w1, b1, w2, b2, w3, b3);
        else    prep_body<0>(w1, b1, w2, b2, w3, b3);
    } else {
        if (dt) qprep_body<1>(query, ipw, ipb, sq);
        else    qprep_body<0>(query, ipw, ipb, sq);
    }
}

// ---------------- stage 1: 16 agents/block, 4 waves, 4 barriers ----------------
// LDS (shorts). Region A: feat [16][FEAT_AS], reused as h2. Region B: h1
// [16][H1_AS], reused as c3 (mean, [ag][128]+pad). Measured strides.
#define FEAT_RS 24     // rows t=0..21 (20/21 zero); 48 B
#define FEAT_AS 568    // 1136 B == -4 banks (mod 32)
#define H1_RS 40       // rows t=0..10 (10 zero); 80 B
#define H1_AS 440      // 880 B == -4 banks
#define H2_RS 72       // rows r=0..6 (0,6 zero); 144 B
#define H2_AS 504      // 1008 B == -4 banks
#define C3_AS 136      // mean row: 128 + 8 pad; 272 B == +4 banks
#define OFF_H1 9088    // shorts = 16*FEAT_AS
#define OFF_VALID 32256 // bytes
#define SMEM_BYTES 32320 // -> 32768 alloc => 5 blocks/CU (LDS cap)

#define MFMA16(a, b, c) __builtin_amdgcn_mfma_f32_16x16x32_bf16((a), (b), (c), 0, 0, 0)

__device__ __forceinline__ uint2 pack_relu(f4v acc, f4v bia) {
    unsigned int lo = f2bu(fmaxf(acc[0] + bia[0], 0.f)) | ((unsigned int)f2bu(fmaxf(acc[1] + bia[1], 0.f)) << 16);
    unsigned int hi = f2bu(fmaxf(acc[2] + bia[2], 0.f)) | ((unsigned int)f2bu(fmaxf(acc[3] + bia[3], 0.f)) << 16);
    return make_uint2(lo, hi);
}

template <int DT>
__device__ __forceinline__ void stage1_body(
    const void* pos, const void* heading, const void* vel, const void* shp,
    const void* vmask, const int* category, const void* type_emb, void* out,
    char* smem, long agent0) {
    short* feat = (short*)smem;               // region A
    short* h1   = (short*)smem + OFF_H1;      // region B
    short* h2   = (short*)smem;               // region A reuse (feat dead after conv1)
    short* c3   = (short*)smem + OFF_H1;      // region B reuse (h1 dead after conv2)
    int* s_valid = (int*)(smem + OFF_VALID);

    const int tid = threadIdx.x;
    const int wave = tid >> 6, lane = tid & 63;
    const int col = lane & 15, quad = lane >> 4;
    const int mode = g_mask_mode;

    // ---- phase 1: feature build + h1 zero row + per-agent valid (t0-OR) ----
    {
        unsigned int* h1u = (unsigned int*)h1;          // h1 row 10 zero
        h1u[(tid >> 4) * 220 + 200 + (tid & 15)] = 0;
    }
    for (int idx = tid; idx < 16 * 22; idx += 256) {
        int ag = idx / 22, t = idx % 22;
        short* row = feat + ag * FEAT_AS + t * FEAT_RS;
        long agl = agent0 + ag;
        if (t == 0) {                       // direct OR over the agent's 21 masks
            long b0 = agl * TT;
            int v = 0;
#pragma unroll
            for (int tt = 0; tt < TT; tt++)
                v |= mask_at(vmask, b0 + tt, mode) ? 1 : 0;
            s_valid[ag] = v;
        }
        if (t >= 20) {
            *(uint4*)row = make_uint4(0, 0, 0, 0);
            *(uint4*)(row + 8) = make_uint4(0, 0, 0, 0);
        } else {
            long base = agl * TT + t;
            bool vmt = mask_at(vmask, base, mode);
            bool m2 = vmt && mask_at(vmask, base + 1, mode);
            float2 pa = ldf2<DT>(pos, base * 2), pb = ldf2<DT>(pos, base * 2 + 2);
            float2 va = ldf2<DT>(vel, base * 2), vb = ldf2<DT>(vel, base * 2 + 2);
            float hh0 = ldf<DT>(heading, base), hh1 = ldf<DT>(heading, base + 1);
            float2 sv = ldf2<DT>(shp, base * 2 + 2);
            float dh = m2 ? (hh1 - hh0) : 0.f;      // masked: cos=1, sin=0 (ref)
            float sn, cn;
            __sincosf(dh, &sn, &cn);
            unsigned int p0 = f2bu(m2 ? pb.x - pa.x : 0.f) | ((unsigned int)f2bu(m2 ? pb.y - pa.y : 0.f) << 16);
            unsigned int p1 = f2bu(m2 ? vb.x - va.x : 0.f) | ((unsigned int)f2bu(m2 ? vb.y - va.y : 0.f) << 16);
            unsigned int p2 = f2bu(cn) | ((unsigned int)f2bu(sn) << 16);
            unsigned int p3 = f2bu(sv.x) | ((unsigned int)f2bu(sv.y) << 16);
            unsigned int p4 = (unsigned int)f2bu(m2 ? 1.f : 0.f);
            *(uint4*)row = make_uint4(p0, p1, p2, p3);
            *(uint4*)(row + 8) = make_uint4(p4, 0, 0, 0);
        }
    }
    bar_lds();

    // ---- conv1: both Mt per wave (A in regs), p = wave,wave+4,wave+8 ----
    {
        s8v a00 = *(const s8v*)(g_w1p + col * 64 + quad * 8);
        s8v a01 = *(const s8v*)(g_w1p + col * 64 + 32 + quad * 8);
        s8v a10 = *(const s8v*)(g_w1p + (16 + col) * 64 + quad * 8);
        s8v a11 = *(const s8v*)(g_w1p + (16 + col) * 64 + 32 + quad * 8);
        f4v bia0 = *(const f4v*)(g_b1 + quad * 4);
        f4v bia1 = *(const f4v*)(g_b1 + 16 + quad * 4);
        int k0 = quad * 8, k1 = 32 + quad * 8;
        int tap0 = k0 >> 4, ic0 = k0 & 15;
        int tap1 = k1 >> 4, ic1 = k1 & 15;
        const short* agbase = feat + col * FEAT_AS;
        for (int p = wave; p < 10; p += 4) {
            const short* bb = agbase + 2 * p * FEAT_RS;
            s8v b0 = *(const s8v*)(bb + tap0 * FEAT_RS + ic0);
            s8v b1 = *(const s8v*)(bb + tap1 * FEAT_RS + ic1);
            f4v acc0 = {0.f, 0.f, 0.f, 0.f}, acc1 = {0.f, 0.f, 0.f, 0.f};
            acc0 = MFMA16(a00, b0, acc0); acc0 = MFMA16(a01, b1, acc0);
            acc1 = MFMA16(a10, b0, acc1); acc1 = MFMA16(a11, b1, acc1);
            short* wr = h1 + col * H1_AS + p * H1_RS + quad * 4;
            *(uint2*)wr = pack_relu(acc0, bia0);
            *(uint2*)(wr + 16) = pack_relu(acc1, bia1);
        }
    }
    bar_lds();

    // ---- conv2: wave = Mt-pair x p-half; b[3] shared across the 2 Mt ----
    {
        unsigned int* h2u = (unsigned int*)h2;
        for (int i = tid; i < 1024; i += 256) {
            int a2 = i >> 6, r = (i >> 5) & 1, cc = i & 31;
            h2u[a2 * 252 + r * 216 + cc] = 0;
        }
        int mt2 = wave >> 1;                   // Mt pair {2*mt2, 2*mt2+1}
        int nh = wave & 1;                     // p subset: 0 -> 0..2, 1 -> 3..4
        s8v a0[3], a1[3];
#pragma unroll
        for (int ks = 0; ks < 3; ks++) {
            a0[ks] = *(const s8v*)(g_w2p + ((mt2 * 2) * 16 + col) * 96 + ks * 32 + quad * 8);
            a1[ks] = *(const s8v*)(g_w2p + ((mt2 * 2 + 1) * 16 + col) * 96 + ks * 32 + quad * 8);
        }
        f4v bia0 = *(const f4v*)(g_b2 + (mt2 * 2) * 16 + quad * 4);
        f4v bia1 = *(const f4v*)(g_b2 + (mt2 * 2 + 1) * 16 + quad * 4);
        int pbeg = nh * 3, pend = nh ? 5 : 3;
        for (int p = pbeg; p < pend; p++) {
            const short* bb = h1 + col * H1_AS + 2 * p * H1_RS + quad * 8;
            s8v b0 = *(const s8v*)(bb);
            s8v b1 = *(const s8v*)(bb + H1_RS);
            s8v b2 = *(const s8v*)(bb + 2 * H1_RS);
            f4v acc0 = {0.f, 0.f, 0.f, 0.f}, acc1 = {0.f, 0.f, 0.f, 0.f};
            acc0 = MFMA16(a0[0], b0, acc0); acc0 = MFMA16(a0[1], b1, acc0); acc0 = MFMA16(a0[2], b2, acc0);
            acc1 = MFMA16(a1[0], b0, acc1); acc1 = MFMA16(a1[1], b1, acc1); acc1 = MFMA16(a1[2], b2, acc1);
            short* wr = h2 + col * H2_AS + (p + 1) * H2_RS + (mt2 * 2) * 16 + quad * 4;
            *(uint2*)wr = pack_relu(acc0, bia0);
            *(uint2*)(wr + 16) = pack_relu(acc1, bia1);
        }
    }
    bar_lds();

    // ---- conv3: BOTH Mt A-sets hoisted (12 global, outside loops); b[6]
    //      shared across the Mt pair per p; in-reg f32 relu-mean over p ----
    {
        int Mt0 = wave * 2, Mt1 = Mt0 + 1;
        s8v a0[6], a1[6];
#pragma unroll
        for (int ks = 0; ks < 6; ks++) {
            a0[ks] = *(const s8v*)(g_w3p + (Mt0 * 16 + col) * 192 + ks * 32 + quad * 8);
            a1[ks] = *(const s8v*)(g_w3p + (Mt1 * 16 + col) * 192 + ks * 32 + quad * 8);
        }
        f4v bia0 = *(const f4v*)(g_b3 + Mt0 * 16 + quad * 4);
        f4v bia1 = *(const f4v*)(g_b3 + Mt1 * 16 + quad * 4);
        f4v m0 = {0.f, 0.f, 0.f, 0.f}, m1 = {0.f, 0.f, 0.f, 0.f};
#pragma unroll
        for (int p = 0; p < 3; p++) {
            s8v b[6];
#pragma unroll
            for (int ks = 0; ks < 6; ks++) {
                int kg = ks * 32 + quad * 8;
                int tap = kg >> 6, ic = kg & 63;
                b[ks] = *(const s8v*)(h2 + col * H2_AS + (2 * p + tap) * H2_RS + ic);
            }
            f4v acc0 = {0.f, 0.f, 0.f, 0.f}, acc1 = {0.f, 0.f, 0.f, 0.f};
#pragma unroll
            for (int ks = 0; ks < 6; ks++) {
                acc0 = MFMA16(a0[ks], b[ks], acc0);
                acc1 = MFMA16(a1[ks], b[ks], acc1);
            }
#pragma unroll
            for (int j = 0; j < 4; j++) {
                m0[j] += fmaxf(acc0[j] + bia0[j], 0.f);
                m1[j] += fmaxf(acc1[j] + bia1[j], 0.f);
            }
        }
        unsigned int lo0 = f2bu(m0[0] * (1.f / 3.f)) | ((unsigned int)f2bu(m0[1] * (1.f / 3.f)) << 16);
        unsigned int hi0 = f2bu(m0[2] * (1.f / 3.f)) | ((unsigned int)f2bu(m0[3] * (1.f / 3.f)) << 16);
        unsigned int lo1 = f2bu(m1[0] * (1.f / 3.f)) | ((unsigned int)f2bu(m1[1] * (1.f / 3.f)) << 16);
        unsigned int hi1 = f2bu(m1[2] * (1.f / 3.f)) | ((unsigned int)f2bu(m1[3] * (1.f / 3.f)) << 16);
        short* wr = c3 + col * C3_AS + Mt0 * 16 + quad * 4;
        *(uint2*)wr = make_uint2(lo0, hi0);
        *(uint2*)(wr + 16) = make_uint2(lo1, hi1);
    }
    bar_lds();

    // ---- epilogue: read mean row, valid mask, + type_emb (coalesced rows) ----
    {
        int ag = tid >> 4;
        int ocg = (tid & 15) * 8;
        s8v x = *(const s8v*)(c3 + ag * C3_AS + ocg);
        int valid = s_valid[ag];
        long agl = agent0 + ag;
        int cat = category[agl];
        float vals[8];
#pragma unroll
        for (int j = 0; j < 8; j++)
            vals[j] = valid ? bu2f((unsigned short)x[j]) : 0.f;
        if (DT) {
            s8v te = *(const s8v*)((const bf16*)type_emb + (long)cat * 128 + ocg);
            s8v o;
#pragma unroll
            for (int j = 0; j < 8; j++)
                o[j] = (short)f2bu(vals[j] + bu2f((unsigned short)te[j]));
            *(s8v*)((bf16*)out + agl * 128 + ocg) = o;
        } else {
            const float4* tep = (const float4*)((const float*)type_emb + (long)cat * 128 + ocg);
            float4 t0 = tep[0], t1 = tep[1];
            float4 o0 = make_float4(vals[0] + t0.x, vals[1] + t0.y, vals[2] + t0.z, vals[3] + t0.w);
            float4 o1 = make_float4(vals[4] + t1.x, vals[5] + t1.y, vals[6] + t1.z, vals[7] + t1.w);
            float4* op = (float4*)((float*)out + agl * 128 + ocg);
            op[0] = o0; op[1] = o1;
        }
    }
}

__global__ __launch_bounds__(256) void stage1_kernel(
    const void* __restrict__ pos, const void* __restrict__ heading,
    const void* __restrict__ vel, const void* __restrict__ shp,
    const void* __restrict__ vmask, const int* __restrict__ category,
    const void* __restrict__ type_emb, void* __restrict__ out) {
    __shared__ __align__(16) char smem[SMEM_BYTES];
    long agent0 = (long)blockIdx.x * 16;
    if (g_dtype) stage1_body<1>(pos, heading, vel, shp, vmask, category, type_emb, out, smem, agent0);
    else         stage1_body<0>(pos, heading, vel, shp, vmask, category, type_emb, out, smem, agent0);
}

// ---------------- stage 2 (256 threads): ego cross-attention, overwrites out[b][0] ----------------
template <int DT>
__device__ __forceinline__ void stage2_body(
    const void* cs, const int* category,
    const void* se_w, const void* se_b, const void* pe,
    const void* ipw, const void* ipb, const void* opw, const void* opb,
    const void* type_emb, void* out, float* sm) {
    const int b = blockIdx.x;
    const int tid = threadIdx.x;
    const int d = tid & 127, half = tid >> 7;

    float* s_xe  = sm;                  // [6][128]
    float* s_y   = s_xe + 768;          // [4][128]
    float* s_sc  = s_y + 512;           // [24] (+pad)
    float* s_att = s_sc + 32;           // [24] (+pad)
    float* s_o   = s_att + 32;          // [128]
    float* s_par = s_o + 128;           // [2][128]

    for (int idx = tid; idx < 768; idx += 256) {
        int s = idx >> 7, dd = idx & 127;
        float ego = ldf<DT>(cs, b * 6 + s);
        s_xe[idx] = fmaf(ego, ldf<DT>(se_w, s * 128 + dd),
                         ldf<DT>(se_b, s * 128 + dd) + ldf<DT>(pe, s * 128 + dd));
    }
    __syncthreads();

    if (tid < 96) {
        int g = tid >> 2, lig = tid & 3;
        int h = g / 6, s = g - h * 6;
        const float* xr = s_xe + s * 128 + lig * 32;
        const float* wr = g_wqk + h * 128 + lig * 32;
        float t = 0.f;
#pragma unroll
        for (int e = 0; e < 32; e++) t = fmaf(xr[e], wr[e], t);
        t += __shfl_xor(t, 1, 4);
        t += __shfl_xor(t, 2, 4);
        if (lig == 0) s_sc[g] = (t + g_qb[h]) * 0.17677669529663687f;
    }
    __syncthreads();

    if (tid < 4) {
        float mx = -1e30f;
#pragma unroll
        for (int s = 0; s < 6; s++) mx = fmaxf(mx, s_sc[tid * 6 + s]);
        float sum = 0.f, ex[6];
#pragma unroll
        for (int s = 0; s < 6; s++) { ex[s] = expf(s_sc[tid * 6 + s] - mx); sum += ex[s]; }
        float inv = 1.f / sum;
#pragma unroll
        for (int s = 0; s < 6; s++) s_att[tid * 6 + s] = ex[s] * inv;
    }
    __syncthreads();

    for (int idx = tid; idx < 512; idx += 256) {
        int h = idx >> 7, e = idx & 127;
        float y = 0.f;
#pragma unroll
        for (int s = 0; s < 6; s++) y = fmaf(s_att[h * 6 + s], s_xe[s * 128 + e], y);
        s_y[idx] = y;
    }
    __syncthreads();

    {
        int h = d >> 5;
        const float* yr = s_y + h * 128 + half * 64;
        s_par[half * 128 + d] = rowdot64<DT>(ipw, (long)(256 + d) * 128 + half * 64, yr);
    }
    __syncthreads();
    if (half == 0) s_o[d] = s_par[d] + s_par[128 + d] + ldf<DT>(ipb, 256 + d);
    __syncthreads();

    {
        const float* orr = s_o + half * 64;
        s_par[half * 128 + d] = rowdot64<DT>(opw, (long)d * 128 + half * 64, orr);
    }
    __syncthreads();
    if (half == 0) {
        float x = s_par[d] + s_par[128 + d] + ldf<DT>(opb, d);
        int cat = category[(long)b * AAG];
        stf<DT>(out, (long)b * AAG * 128 + d, x + ldf<DT>(type_emb, cat * 128 + d));
    }
}

__global__ __launch_bounds__(256) void stage2_kernel(
    const void* __restrict__ cs, const int* __restrict__ category,
    const void* __restrict__ se_w, const void* __restrict__ se_b,
    const void* __restrict__ pe,
    const void* __restrict__ ipw, const void* __restrict__ ipb,
    const void* __restrict__ opw, const void* __restrict__ opb,
    const void* __restrict__ type_emb, void* __restrict__ out) {
    __shared__ float sm[1728];
    if (g_dtype) stage2_body<1>(cs, category, se_w, se_b, pe, ipw, ipb, opw, opb, type_emb, out, sm);
    else         stage2_body<0>(cs, category, se_w, se_b, pe, ipw, ipb, opw, opb, type_emb, out, sm);
}

extern "C" void kernel_launch(void* const* d_in, const int* in_sizes, int n_in,
                              void* d_out, int out_size, void* d_ws, size_t ws_size,
                              hipStream_t stream) {
    const void* position      = d_in[0];
    const void* heading       = d_in[1];
    const void* velocity      = d_in[2];
    const void* shape         = d_in[3];
    const void* current_state = d_in[4];
    const int*  category      = (const int*)d_in[5];
    const void* valid_mask    = d_in[6];
    const void* conv1_w = d_in[7];
    const void* conv1_b = d_in[8];
    const void* conv2_w = d_in[9];
    const void* conv2_b = d_in[10];
    const void* conv3_w = d_in[11];
    const void* conv3_b = d_in[12];
    const void* se_w    = d_in[13];
    const void* se_b    = d_in[14];
    const void* pos_embed = d_in[15];
    const void* query     = d_in[16];
    const void* in_proj_w = d_in[17];
    const void* in_proj_b = d_in[18];
    const void* out_proj_w = d_in[19];
    const void* out_proj_b = d_in[20];
    const void* type_emb   = d_in[21];

    hipLaunchKernelGGL(prep_kernel, dim3(65), dim3(256), 0, stream,
                       (const unsigned int*)position, (const unsigned char*)valid_mask,
                       conv1_w, conv1_b, conv2_w, conv2_b, conv3_w, conv3_b,
                       query, in_proj_w, in_proj_b);

    hipLaunchKernelGGL(stage1_kernel, dim3(NAG / 16), dim3(256), 0, stream,
                       position, heading, velocity, shape, valid_mask, category,
                       type_emb, d_out);

    hipLaunchKernelGGL(stage2_kernel, dim3(BB), dim3(256), 0, stream,
                       current_state, category, se_w, se_b, pos_embed,
                       in_proj_w, in_proj_b, out_proj_w, out_proj_b, type_emb, d_out);
}

// Round 10
// 352.821 us; speedup vs baseline: 1.0331x; 1.0146x over previous
//
#include <hip/hip_runtime.h>
#include <hip/hip_bf16.h>

// AgentEncoder: B=256, A=512, T=21, DIM=128, SC=6, NHEAD=4, HD=32
// Round 10: disciplined recompose of measured-best components.
//  - stage1: round-1 EXACT body (131us measured; every restructure r3/r5/r8/r9
//    regressed) + the r6-validated-neutral fold: t0-OR valid + h1-zero-row in
//    the feature phase => 4 plain __syncthreads, no atomics.
//  - prep/stage2: round-9 forms (fused detect+prep+q-fold; slim stage2 with
//    q/k pre-folded scores and softmax-sum=1 V-fold); 3 dispatches,
//    overhead measured ~152us across r6/r7/r9.
// r9 lesson logged: compiler sinks "hoisted" loads when no barrier pins them;
// VGPR_Count is the tell. LDS-op count exonerated as limiter (r8/r9).

#define BB 256
#define AAG 512
#define TT 21
#define NAG (BB * AAG)

typedef __hip_bfloat16 bf16;
typedef __attribute__((ext_vector_type(8))) short s8v;   // 8 bf16 = 4 VGPR
typedef __attribute__((ext_vector_type(4))) float f4v;   // mfma acc

__device__ int g_dtype;        // 1 = bf16 inputs, 0 = f32 inputs
__device__ int g_mask_mode;    // 0=i32, 1=u8, 2=f32, 3=bf16
__device__ __align__(16) short g_w1p[32 * 64];    // [oc][k=tap*16+ic], pad0
__device__ __align__(16) short g_w2p[64 * 96];    // [oc][k=tap*32+ic]
__device__ __align__(16) short g_w3p[128 * 192];  // [oc][k=tap*64+ic]
__device__ __align__(16) float g_b1[32];
__device__ __align__(16) float g_b2[64];
__device__ __align__(16) float g_b3[128];
__device__ __align__(16) float g_wqk[4 * 128];    // per-head q-folded Wk
__device__ __align__(16) float g_qb[4];           // per-head q.bk

template <int DT>
__device__ __forceinline__ float ldf(const void* p, long i) {
    if (DT) return __bfloat162float(((const bf16*)p)[i]);
    return ((const float*)p)[i];
}
template <int DT>
__device__ __forceinline__ void stf(void* p, long i, float v) {
    if (DT) ((bf16*)p)[i] = __float2bfloat16(v);
    else    ((float*)p)[i] = v;
}
__device__ __forceinline__ unsigned short f2bu(float x) {
    bf16 b = __float2bfloat16(x);
    union { bf16 b; unsigned short u; } cv; cv.b = b; return cv.u;
}
__device__ __forceinline__ float bu2f(unsigned short u) {
    union { unsigned int i; float f; } cv; cv.i = ((unsigned int)u) << 16; return cv.f;
}
template <int DT>
__device__ __forceinline__ float2 ldf2(const void* p, long i) {  // i even
    if (DT) {
        unsigned int u = *(const unsigned int*)((const bf16*)p + i);
        return make_float2(bu2f((unsigned short)(u & 0xffffu)),
                           bu2f((unsigned short)(u >> 16)));
    }
    return *(const float2*)((const float*)p + i);
}
__device__ __forceinline__ bool mask_at(const void* p, long i, int mode) {
    if (mode == 0) return ((const int*)p)[i] != 0;
    if (mode == 1) return ((const unsigned char*)p)[i] != 0;
    if (mode == 2) return ((const float*)p)[i] != 0.f;
    return (((const unsigned short*)p)[i] & 0x7fff) != 0;
}

// 64-element row-dot: sum_i W[off+i] * y[i], vectorized 16B loads
template <int DT>
__device__ __forceinline__ float rowdot64(const void* W, long off, const float* y) {
    float acc = 0.f;
    if (DT) {
        const unsigned short* wr = (const unsigned short*)W + off;
#pragma unroll
        for (int i = 0; i < 8; i++) {
            uint4 w = *(const uint4*)(wr + i * 8);
            acc = fmaf(bu2f((unsigned short)(w.x & 0xffffu)), y[i * 8 + 0], acc);
            acc = fmaf(bu2f((unsigned short)(w.x >> 16)),     y[i * 8 + 1], acc);
            acc = fmaf(bu2f((unsigned short)(w.y & 0xffffu)), y[i * 8 + 2], acc);
            acc = fmaf(bu2f((unsigned short)(w.y >> 16)),     y[i * 8 + 3], acc);
            acc = fmaf(bu2f((unsigned short)(w.z & 0xffffu)), y[i * 8 + 4], acc);
            acc = fmaf(bu2f((unsigned short)(w.z >> 16)),     y[i * 8 + 5], acc);
            acc = fmaf(bu2f((unsigned short)(w.w & 0xffffu)), y[i * 8 + 6], acc);
            acc = fmaf(bu2f((unsigned short)(w.w >> 16)),     y[i * 8 + 7], acc);
        }
    } else {
        const float* wr = (const float*)W + off;
#pragma unroll
        for (int i = 0; i < 16; i++) {
            float4 w = *(const float4*)(wr + i * 4);
            acc = fmaf(w.x, y[i * 4 + 0], acc);
            acc = fmaf(w.y, y[i * 4 + 1], acc);
            acc = fmaf(w.z, y[i * 4 + 2], acc);
            acc = fmaf(w.w, y[i * 4 + 3], acc);
        }
    }
    return acc;
}

// ---------------- weight pad/transpose/cast (grid-stride over 64 blocks) ----------------
template <int DT>
__device__ __forceinline__ void prep_body(const void* w1, const void* b1,
                                          const void* w2, const void* b2,
                                          const void* w3, const void* b3) {
    int tid = blockIdx.x * 256 + threadIdx.x;
    const int nt = 64 * 256;
    for (int i = tid; i < 32 * 64; i += nt) {
        int oc = i >> 6, k = i & 63, tap = k >> 4, ic = k & 15;
        float v = (tap < 3 && ic < 9) ? ldf<DT>(w1, oc * 27 + ic * 3 + tap) : 0.f;
        g_w1p[i] = (short)f2bu(v);
    }
    for (int i = tid; i < 64 * 96; i += nt) {
        int oc = i / 96, k = i % 96, tap = k >> 5, ic = k & 31;
        g_w2p[i] = (short)f2bu(ldf<DT>(w2, oc * 96 + ic * 3 + tap));
    }
    for (int i = tid; i < 128 * 192; i += nt) {
        int oc = i / 192, k = i % 192, tap = k >> 6, ic = k & 63;
        g_w3p[i] = (short)f2bu(ldf<DT>(w3, oc * 192 + ic * 3 + tap));
    }
    for (int i = tid; i < 32; i += nt) g_b1[i] = ldf<DT>(b1, i);
    for (int i = tid; i < 64; i += nt) g_b2[i] = ldf<DT>(b2, i);
    for (int i = tid; i < 128; i += nt) g_b3[i] = ldf<DT>(b3, i);
}

// block 64: q = query@Wq^T+bq, then fold through Wk: g_wqk[h][e], g_qb[h]
template <int DT>
__device__ __forceinline__ void qprep_body(const void* query, const void* ipw,
                                           const void* ipb, float* sq) {
    int tid = threadIdx.x;
    if (tid < 128) {
        float acc = ldf<DT>(ipb, tid);
        for (int e = 0; e < 128; e++)
            acc = fmaf(ldf<DT>(query, e), ldf<DT>(ipw, (long)tid * 128 + e), acc);
        sq[tid] = acc;
    }
    __syncthreads();
    int e = tid & 127, hb = tid >> 7;
    for (int h = hb; h < 4; h += 2) {
        float acc = 0.f;
#pragma unroll
        for (int j = 0; j < 32; j++)
            acc = fmaf(sq[h * 32 + j], ldf<DT>(ipw, (long)(128 + h * 32 + j) * 128 + e), acc);
        g_wqk[h * 128 + e] = acc;
    }
    if (tid < 4) {
        float acc = 0.f;
#pragma unroll
        for (int j = 0; j < 32; j++)
            acc = fmaf(sq[tid * 32 + j], ldf<DT>(ipb, 128 + tid * 32 + j), acc);
        g_qb[tid] = acc;
    }
}

// ---------------- launch A: per-block detect + prep + q-fold ----------------
__global__ __launch_bounds__(256) void prep_kernel(
    const unsigned int* __restrict__ pw, const unsigned char* __restrict__ m,
    const void* __restrict__ w1, const void* __restrict__ b1,
    const void* __restrict__ w2, const void* __restrict__ b2,
    const void* __restrict__ w3, const void* __restrict__ b3,
    const void* __restrict__ query, const void* __restrict__ ipw,
    const void* __restrict__ ipb) {
    __shared__ int cls[4];
    __shared__ int mv;
    __shared__ int good;
    __shared__ float sq[128];
    int tid = threadIdx.x;
    if (tid < 4) cls[tid] = 0;
    if (tid == 0) { mv = 0; good = 0; }
    __syncthreads();
    int g = 0;
    for (int i = tid; i < 1024; i += 256) {
        unsigned int w = pw[i];
        unsigned int h0 = w & 0xffffu, h1 = w >> 16;
        unsigned int e0 = (h0 >> 7) & 0xff, e1 = (h1 >> 7) & 0xff;
        if (h0 == 0 || (e0 >= 90 && e0 <= 160)) g++;
        if (h1 == 0 || (e1 >= 90 && e1 <= 160)) g++;
    }
    atomicAdd(&good, g);
    int l0 = 0, l1 = 0, l2 = 0, l3 = 0, lm = 0;
    for (int i = tid; i < 4096; i += 256) {
        int v = m[i];
        if (v) {
            switch (i & 3) { case 0: l0 = 1; break; case 1: l1 = 1; break;
                             case 2: l2 = 1; break; default: l3 = 1; }
            if (v > lm) lm = v;
        }
    }
    if (l0) atomicOr(&cls[0], 1);
    if (l1) atomicOr(&cls[1], 1);
    if (l2) atomicOr(&cls[2], 1);
    if (l3) atomicOr(&cls[3], 1);
    atomicMax(&mv, lm);
    __syncthreads();
    int dt = (good >= 1740) ? 1 : 0;
    int mode;
    if (!cls[1] && !cls[2] && !cls[3]) mode = 0;
    else if (!cls[0] && !cls[1])       mode = 2;
    else if (mv <= 1)                  mode = 1;
    else                               mode = 3;
    if (blockIdx.x == 0 && tid == 0) { g_dtype = dt; g_mask_mode = mode; }

    if (blockIdx.x < 64) {
        if (dt) prep_body<1>(w1, b1, w2, b2, w3, b3);
        else    prep_body<0>(w1, b1, w2, b2, w3, b3);
    } else {
        if (dt) qprep_body<1>(query, ipw, ipb, sq);
        else    qprep_body<0>(query, ipw, ipb, sq);
    }
}

// ---------------- stage 1 (round-1 exact): 16 agents/block, 4 waves ----------------
// LDS (shorts). Region A: feat [16][FEAT_AS], reused as h2. Region B: h1
// [16][H1_AS], reused as c3. Agent strides == +-4 banks (mod 32): lanes step
// the AGENT axis (ag = col) => 2-way bank aliasing (free, m136).
#define FEAT_RS 24     // rows t=0..21 (20/21 zero); 48 B
#define FEAT_AS 568    // 1136 B == -4 banks (mod 32)
#define H1_RS 40       // rows t=0..10 (10 zero); 80 B
#define H1_AS 440      // 880 B == -4 banks
#define H2_RS 72       // rows r=0..6 (0,6 zero); 144 B
#define H2_AS 504      // 1008 B == -4 banks
#define C3_AS 392      // 3*128 + 8 pad; 784 B == +4 banks
#define OFF_H1 9088    // shorts = 16*FEAT_AS
#define OFF_VALID 32256 // bytes
#define SMEM_BYTES 32320 // -> 32768 alloc => 5 blocks/CU (LDS cap)

#define MFMA16(a, b, c) __builtin_amdgcn_mfma_f32_16x16x32_bf16((a), (b), (c), 0, 0, 0)

template <int DT>
__device__ __forceinline__ void stage1_body(
    const void* pos, const void* heading, const void* vel, const void* shp,
    const void* vmask, const int* category, const void* type_emb, void* out,
    char* smem, long agent0) {
    short* feat = (short*)smem;               // region A
    short* h1   = (short*)smem + OFF_H1;      // region B
    short* h2   = (short*)smem;               // region A reuse (feat dead after conv1)
    short* c3   = (short*)smem + OFF_H1;      // region B reuse (h1 dead after conv2)
    int* s_valid = (int*)(smem + OFF_VALID);

    const int tid = threadIdx.x;
    const int wave = tid >> 6, lane = tid & 63;
    const int col = lane & 15, quad = lane >> 4;
    const int mode = g_mask_mode;

    // ---- phase 1: feature build + h1 zero row + per-agent valid (t0-OR) ----
    {
        unsigned int* h1u = (unsigned int*)h1;          // h1 row 10 zero
        h1u[(tid >> 4) * 220 + 200 + (tid & 15)] = 0;
    }
    for (int idx = tid; idx < 16 * 22; idx += 256) {
        int ag = idx / 22, t = idx % 22;
        short* row = feat + ag * FEAT_AS + t * FEAT_RS;
        long agl = agent0 + ag;
        if (t == 0) {                       // direct OR over the agent's 21 masks
            long b0 = agl * TT;
            int v = 0;
#pragma unroll
            for (int tt = 0; tt < TT; tt++)
                v |= mask_at(vmask, b0 + tt, mode) ? 1 : 0;
            s_valid[ag] = v;
        }
        if (t >= 20) {
            *(uint4*)row = make_uint4(0, 0, 0, 0);
            *(uint4*)(row + 8) = make_uint4(0, 0, 0, 0);
        } else {
            long base = agl * TT + t;
            bool vmt = mask_at(vmask, base, mode);
            bool m2 = vmt && mask_at(vmask, base + 1, mode);
            float2 pa = ldf2<DT>(pos, base * 2), pb = ldf2<DT>(pos, base * 2 + 2);
            float2 va = ldf2<DT>(vel, base * 2), vb = ldf2<DT>(vel, base * 2 + 2);
            float hh0 = ldf<DT>(heading, base), hh1 = ldf<DT>(heading, base + 1);
            float2 sv = ldf2<DT>(shp, base * 2 + 2);
            float dh = m2 ? (hh1 - hh0) : 0.f;      // masked: cos=1, sin=0 (ref)
            float sn, cn;
            __sincosf(dh, &sn, &cn);
            unsigned int p0 = f2bu(m2 ? pb.x - pa.x : 0.f) | ((unsigned int)f2bu(m2 ? pb.y - pa.y : 0.f) << 16);
            unsigned int p1 = f2bu(m2 ? vb.x - va.x : 0.f) | ((unsigned int)f2bu(m2 ? vb.y - va.y : 0.f) << 16);
            unsigned int p2 = f2bu(cn) | ((unsigned int)f2bu(sn) << 16);
            unsigned int p3 = f2bu(sv.x) | ((unsigned int)f2bu(sv.y) << 16);
            unsigned int p4 = (unsigned int)f2bu(m2 ? 1.f : 0.f);
            *(uint4*)row = make_uint4(p0, p1, p2, p3);
            *(uint4*)(row + 8) = make_uint4(p4, 0, 0, 0);
        }
    }
    __syncthreads();

    // ---- conv1: M=32 (2 Mt), K=64, N=16ag x 10p => ag=col, p per-iter ----
    {
        int Mt = wave >> 1;
        int oc = Mt * 16 + col;
        s8v a0 = *(const s8v*)(g_w1p + oc * 64 + quad * 8);
        s8v a1 = *(const s8v*)(g_w1p + oc * 64 + 32 + quad * 8);
        int k0 = quad * 8, k1 = 32 + quad * 8;
        int tap0 = k0 >> 4, ic0 = k0 & 15;
        int tap1 = k1 >> 4, ic1 = k1 & 15;
        int ocr = Mt * 16 + quad * 4;
        f4v bia = *(const f4v*)(g_b1 + ocr);
        int ag = col;
        const short* agbase = feat + ag * FEAT_AS;
#pragma unroll
        for (int i = 0; i < 5; i++) {
            int p = (wave & 1) * 5 + i;
            const short* bb = agbase + 2 * p * FEAT_RS;
            s8v b0 = *(const s8v*)(bb + tap0 * FEAT_RS + ic0);
            s8v b1 = *(const s8v*)(bb + tap1 * FEAT_RS + ic1);
            f4v acc = {0.f, 0.f, 0.f, 0.f};
            acc = MFMA16(a0, b0, acc);
            acc = MFMA16(a1, b1, acc);
            unsigned int lo = f2bu(fmaxf(acc[0] + bia[0], 0.f)) | ((unsigned int)f2bu(fmaxf(acc[1] + bia[1], 0.f)) << 16);
            unsigned int hi = f2bu(fmaxf(acc[2] + bia[2], 0.f)) | ((unsigned int)f2bu(fmaxf(acc[3] + bia[3], 0.f)) << 16);
            *(uint2*)(h1 + ag * H1_AS + p * H1_RS + ocr) = make_uint2(lo, hi);
        }
    }
    __syncthreads();

    // ---- conv2: M=64 (4 Mt), K=96, N=16ag x 5p => ag=col, p=Nt. Zero h2 pad
    //      rows 0 & 6 first (region A: feat dead) ----
    {
        unsigned int* h2u = (unsigned int*)h2;
        for (int i = tid; i < 1024; i += 256) {
            int a2 = i >> 6, r = (i >> 5) & 1, cc = i & 31;
            h2u[a2 * 252 + r * 216 + cc] = 0;
        }
        int Mt = wave;
        int oc = Mt * 16 + col;
        s8v a[3];
#pragma unroll
        for (int ks = 0; ks < 3; ks++)
            a[ks] = *(const s8v*)(g_w2p + oc * 96 + ks * 32 + quad * 8);
        int ocr = Mt * 16 + quad * 4;
        f4v bia = *(const f4v*)(g_b2 + ocr);
        int ag = col;
#pragma unroll
        for (int p = 0; p < 5; p++) {
            f4v acc = {0.f, 0.f, 0.f, 0.f};
#pragma unroll
            for (int ks = 0; ks < 3; ks++) {
                s8v b = *(const s8v*)(h1 + ag * H1_AS + (2 * p + ks) * H1_RS + quad * 8);
                acc = MFMA16(a[ks], b, acc);
            }
            unsigned int lo = f2bu(fmaxf(acc[0] + bia[0], 0.f)) | ((unsigned int)f2bu(fmaxf(acc[1] + bia[1], 0.f)) << 16);
            unsigned int hi = f2bu(fmaxf(acc[2] + bia[2], 0.f)) | ((unsigned int)f2bu(fmaxf(acc[3] + bia[3], 0.f)) << 16);
            *(uint2*)(h2 + ag * H2_AS + (p + 1) * H2_RS + ocr) = make_uint2(lo, hi);
        }
    }
    __syncthreads();

    // ---- conv3: M=128 (8 Mt, 2/wave), K=192 (6 slices), N=16ag x 3p ----
#pragma unroll
    for (int m2 = 0; m2 < 2; m2++) {
        int Mt = wave * 2 + m2;
        int oc = Mt * 16 + col;
        s8v a[6];
#pragma unroll
        for (int ks = 0; ks < 6; ks++)
            a[ks] = *(const s8v*)(g_w3p + oc * 192 + ks * 32 + quad * 8);
        int ocr = Mt * 16 + quad * 4;
        f4v bia = *(const f4v*)(g_b3 + ocr);
        int ag = col;
#pragma unroll
        for (int p = 0; p < 3; p++) {
            f4v acc = {0.f, 0.f, 0.f, 0.f};
#pragma unroll
            for (int ks = 0; ks < 6; ks++) {
                int kg = ks * 32 + quad * 8;
                int tap = kg >> 6, ic = kg & 63;
                s8v b = *(const s8v*)(h2 + ag * H2_AS + (2 * p + tap) * H2_RS + ic);
                acc = MFMA16(a[ks], b, acc);
            }
            unsigned int lo = f2bu(fmaxf(acc[0] + bia[0], 0.f)) | ((unsigned int)f2bu(fmaxf(acc[1] + bia[1], 0.f)) << 16);
            unsigned int hi = f2bu(fmaxf(acc[2] + bia[2], 0.f)) | ((unsigned int)f2bu(fmaxf(acc[3] + bia[3], 0.f)) << 16);
            *(uint2*)(c3 + ag * C3_AS + p * 128 + ocr) = make_uint2(lo, hi);
        }
    }
    __syncthreads();

    // ---- epilogue: mean over 3 p, valid mask, + type_emb (coalesced rows) ----
    {
        int ag = tid >> 4;
        int ocg = (tid & 15) * 8;
        const short* cb = c3 + ag * C3_AS;
        s8v x0 = *(const s8v*)(cb + ocg);
        s8v x1 = *(const s8v*)(cb + 128 + ocg);
        s8v x2 = *(const s8v*)(cb + 256 + ocg);
        int valid = s_valid[ag];
        long agl = agent0 + ag;
        int cat = category[agl];
        float vals[8];
#pragma unroll
        for (int j = 0; j < 8; j++) {
            float m = (bu2f((unsigned short)x0[j]) + bu2f((unsigned short)x1[j]) +
                       bu2f((unsigned short)x2[j])) * (1.f / 3.f);
            vals[j] = valid ? m : 0.f;
        }
        if (DT) {
            s8v te = *(const s8v*)((const bf16*)type_emb + (long)cat * 128 + ocg);
            s8v o;
#pragma unroll
            for (int j = 0; j < 8; j++)
                o[j] = (short)f2bu(vals[j] + bu2f((unsigned short)te[j]));
            *(s8v*)((bf16*)out + agl * 128 + ocg) = o;
        } else {
            const float4* tep = (const float4*)((const float*)type_emb + (long)cat * 128 + ocg);
            float4 t0 = tep[0], t1 = tep[1];
            float4 o0 = make_float4(vals[0] + t0.x, vals[1] + t0.y, vals[2] + t0.z, vals[3] + t0.w);
            float4 o1 = make_float4(vals[4] + t1.x, vals[5] + t1.y, vals[6] + t1.z, vals[7] + t1.w);
            float4* op = (float4*)((float*)out + agl * 128 + ocg);
            op[0] = o0; op[1] = o1;
        }
    }
}

__global__ __launch_bounds__(256) void stage1_kernel(
    const void* __restrict__ pos, const void* __restrict__ heading,
    const void* __restrict__ vel, const void* __restrict__ shp,
    const void* __restrict__ vmask, const int* __restrict__ category,
    const void* __restrict__ type_emb, void* __restrict__ out) {
    __shared__ __align__(16) char smem[SMEM_BYTES];
    long agent0 = (long)blockIdx.x * 16;
    if (g_dtype) stage1_body<1>(pos, heading, vel, shp, vmask, category, type_emb, out, smem, agent0);
    else         stage1_body<0>(pos, heading, vel, shp, vmask, category, type_emb, out, smem, agent0);
}

// ---------------- stage 2 (256 threads): ego cross-attention, overwrites out[b][0] ----------------
template <int DT>
__device__ __forceinline__ void stage2_body(
    const void* cs, const int* category,
    const void* se_w, const void* se_b, const void* pe,
    const void* ipw, const void* ipb, const void* opw, const void* opb,
    const void* type_emb, void* out, float* sm) {
    const int b = blockIdx.x;
    const int tid = threadIdx.x;
    const int d = tid & 127, half = tid >> 7;

    float* s_xe  = sm;                  // [6][128]
    float* s_y   = s_xe + 768;          // [4][128]
    float* s_sc  = s_y + 512;           // [24] (+pad)
    float* s_att = s_sc + 32;           // [24] (+pad)
    float* s_o   = s_att + 32;          // [128]
    float* s_par = s_o + 128;           // [2][128]

    for (int idx = tid; idx < 768; idx += 256) {
        int s = idx >> 7, dd = idx & 127;
        float ego = ldf<DT>(cs, b * 6 + s);
        s_xe[idx] = fmaf(ego, ldf<DT>(se_w, s * 128 + dd),
                         ldf<DT>(se_b, s * 128 + dd) + ldf<DT>(pe, s * 128 + dd));
    }
    __syncthreads();

    if (tid < 96) {
        int g = tid >> 2, lig = tid & 3;
        int h = g / 6, s = g - h * 6;
        const float* xr = s_xe + s * 128 + lig * 32;
        const float* wr = g_wqk + h * 128 + lig * 32;
        float t = 0.f;
#pragma unroll
        for (int e = 0; e < 32; e++) t = fmaf(xr[e], wr[e], t);
        t += __shfl_xor(t, 1, 4);
        t += __shfl_xor(t, 2, 4);
        if (lig == 0) s_sc[g] = (t + g_qb[h]) * 0.17677669529663687f;
    }
    __syncthreads();

    if (tid < 4) {
        float mx = -1e30f;
#pragma unroll
        for (int s = 0; s < 6; s++) mx = fmaxf(mx, s_sc[tid * 6 + s]);
        float sum = 0.f, ex[6];
#pragma unroll
        for (int s = 0; s < 6; s++) { ex[s] = expf(s_sc[tid * 6 + s] - mx); sum += ex[s]; }
        float inv = 1.f / sum;
#pragma unroll
        for (int s = 0; s < 6; s++) s_att[tid * 6 + s] = ex[s] * inv;
    }
    __syncthreads();

    for (int idx = tid; idx < 512; idx += 256) {
        int h = idx >> 7, e = idx & 127;
        float y = 0.f;
#pragma unroll
        for (int s = 0; s < 6; s++) y = fmaf(s_att[h * 6 + s], s_xe[s * 128 + e], y);
        s_y[idx] = y;
    }
    __syncthreads();

    {
        int h = d >> 5;
        const float* yr = s_y + h * 128 + half * 64;
        s_par[half * 128 + d] = rowdot64<DT>(ipw, (long)(256 + d) * 128 + half * 64, yr);
    }
    __syncthreads();
    if (half == 0) s_o[d] = s_par[d] + s_par[128 + d] + ldf<DT>(ipb, 256 + d);
    __syncthreads();

    {
        const float* orr = s_o + half * 64;
        s_par[half * 128 + d] = rowdot64<DT>(opw, (long)d * 128 + half * 64, orr);
    }
    __syncthreads();
    if (half == 0) {
        float x = s_par[d] + s_par[128 + d] + ldf<DT>(opb, d);
        int cat = category[(long)b * AAG];
        stf<DT>(out, (long)b * AAG * 128 + d, x + ldf<DT>(type_emb, cat * 128 + d));
    }
}

__global__ __launch_bounds__(256) void stage2_kernel(
    const void* __restrict__ cs, const int* __restrict__ category,
    const void* __restrict__ se_w, const void* __restrict__ se_b,
    const void* __restrict__ pe,
    const void* __restrict__ ipw, const void* __restrict__ ipb,
    const void* __restrict__ opw, const void* __restrict__ opb,
    const void* __restrict__ type_emb, void* __restrict__ out) {
    __shared__ float sm[1728];
    if (g_dtype) stage2_body<1>(cs, category, se_w, se_b, pe, ipw, ipb, opw, opb, type_emb, out, sm);
    else         stage2_body<0>(cs, category, se_w, se_b, pe, ipw, ipb, opw, opb, type_emb, out, sm);
}

extern "C" void kernel_launch(void* const* d_in, const int* in_sizes, int n_in,
                              void* d_out, int out_size, void* d_ws, size_t ws_size,
                              hipStream_t stream) {
    const void* position      = d_in[0];
    const void* heading       = d_in[1];
    const void* velocity      = d_in[2];
    const void* shape         = d_in[3];
    const void* current_state = d_in[4];
    const int*  category      = (const int*)d_in[5];
    const void* valid_mask    = d_in[6];
    const void* conv1_w = d_in[7];
    const void* conv1_b = d_in[8];
    const void* conv2_w = d_in[9];
    const void* conv2_b = d_in[10];
    const void* conv3_w = d_in[11];
    const void* conv3_b = d_in[12];
    const void* se_w    = d_in[13];
    const void* se_b    = d_in[14];
    const void* pos_embed = d_in[15];
    const void* query     = d_in[16];
    const void* in_proj_w = d_in[17];
    const void* in_proj_b = d_in[18];
    const void* out_proj_w = d_in[19];
    const void* out_proj_b = d_in[20];
    const void* type_emb   = d_in[21];

    hipLaunchKernelGGL(prep_kernel, dim3(65), dim3(256), 0, stream,
                       (const unsigned int*)position, (const unsigned char*)valid_mask,
                       conv1_w, conv1_b, conv2_w, conv2_b, conv3_w, conv3_b,
                       query, in_proj_w, in_proj_b);

    hipLaunchKernelGGL(stage1_kernel, dim3(NAG / 16), dim3(256), 0, stream,
                       position, heading, velocity, shape, valid_mask, category,
                       type_emb, d_out);

    hipLaunchKernelGGL(stage2_kernel, dim3(BB), dim3(256), 0, stream,
                       current_state, category, se_w, se_b, pos_embed,
                       in_proj_w, in_proj_b, out_proj_w, out_proj_b, type_emb, d_out);
}